// Round 1
// baseline (2270.703 us; speedup 1.0000x reference)
//
#include <hip/hip_runtime.h>
#include <hip/hip_bf16.h>

// Problem constants (from reference setup_inputs)
#define NN 32768   // nodes
#define EE 8192    // hyperedges
#define DD 128     // feature dim (D_IN == D_OUT == 128)

typedef short v8s __attribute__((ext_vector_type(8)));   // 8 x bf16 MFMA frag
typedef float v4f __attribute__((ext_vector_type(4)));   // 4 x f32 MFMA acc

__device__ __forceinline__ unsigned short f2bf(float f) {
    unsigned int u = __float_as_uint(f);
    u += 0x7fffu + ((u >> 16) & 1u);   // RNE
    return (unsigned short)(u >> 16);
}

// ---------------------------------------------------------------------------
// Kernel 1: degrees. d_v[n] = sum_e H[n][e], d_e[e] = sum_n H[n][e].
// Grid: (EE/256 col-chunks, NN/512 row-chunks). Block 256 = 4 waves.
// Wave handles 128 rows x 256 cols: lane reads float4, shuffle-reduce row sum,
// per-lane col accumulators -> LDS -> one atomicAdd per col per block.
// ---------------------------------------------------------------------------
__global__ __launch_bounds__(256) void deg_kernel(const float* __restrict__ H,
                                                  float* __restrict__ d_v,
                                                  float* __restrict__ d_e) {
    __shared__ float cl[4 * 256];
    const int tid  = threadIdx.x;
    const int lane = tid & 63;
    const int wave = tid >> 6;
    const int cbase = blockIdx.x * 256;
    const int rbase = blockIdx.y * 512 + wave * 128;

    float c0 = 0.f, c1 = 0.f, c2 = 0.f, c3 = 0.f;
    const float* hp = H + (size_t)rbase * EE + cbase + lane * 4;
    for (int i = 0; i < 128; ++i) {
        const float4 v = *reinterpret_cast<const float4*>(hp + (size_t)i * EE);
        c0 += v.x; c1 += v.y; c2 += v.z; c3 += v.w;
        float rs = v.x + v.y + v.z + v.w;
        rs += __shfl_xor(rs, 1);  rs += __shfl_xor(rs, 2);
        rs += __shfl_xor(rs, 4);  rs += __shfl_xor(rs, 8);
        rs += __shfl_xor(rs, 16); rs += __shfl_xor(rs, 32);
        if (lane == 0) atomicAdd(&d_v[rbase + i], rs);
    }
    cl[wave * 256 + lane * 4 + 0] = c0;
    cl[wave * 256 + lane * 4 + 1] = c1;
    cl[wave * 256 + lane * 4 + 2] = c2;
    cl[wave * 256 + lane * 4 + 3] = c3;
    __syncthreads();
    float s = cl[tid] + cl[256 + tid] + cl[512 + tid] + cl[768 + tid];
    atomicAdd(&d_e[cbase + tid], s);
}

// ---------------------------------------------------------------------------
// Kernel 2: prep. x1bT[d][n] = bf16(x[n][d] / (sqrt(d_v[n]) + 1e-8));
// block 512 additionally converts W (row-major [do][di]) to bf16.
// LDS tile transpose so both global read and write are coalesced.
// ---------------------------------------------------------------------------
__global__ __launch_bounds__(256) void prep_kernel(const float* __restrict__ x,
                                                   const float* __restrict__ W,
                                                   const float* __restrict__ d_v,
                                                   unsigned short* __restrict__ x1bT,
                                                   unsigned short* __restrict__ Wb) {
    if (blockIdx.x == 512) {
        for (int i = threadIdx.x; i < DD * DD; i += 256) Wb[i] = f2bf(W[i]);
        return;
    }
    __shared__ float t[128 * 65];
    const int nb = blockIdx.x * 64;
    for (int i = 0; i < 32; ++i) {
        int idx = i * 256 + threadIdx.x;
        int nl = idx >> 7, d = idx & 127;
        float dv = d_v[nb + nl];
        float val = x[(size_t)(nb + nl) * DD + d] * (1.f / (sqrtf(dv) + 1e-8f));
        t[d * 65 + nl] = val;
    }
    __syncthreads();
    for (int i = 0; i < 32; ++i) {
        int idx = i * 256 + threadIdx.x;
        int nl = idx & 63, d = idx >> 6;
        x1bT[(size_t)d * NN + nb + nl] = f2bf(t[d * 65 + nl]);
    }
}

// ---------------------------------------------------------------------------
// Shared B-staging: fragment-linear LDS layout. Chunk c = s*512 + g*64 + lane
// holds Bsrc[g*16 + (lane&15)][kbase + s*32 + (lane>>4)*8 .. +8] (8 bf16).
// Frag read = one conflict-free ds_read_b128 per (s,g).
// ---------------------------------------------------------------------------
__device__ __forceinline__ void stage_B(const unsigned short* __restrict__ Bsrc,
                                        size_t ld, int kbase,
                                        unsigned short* __restrict__ Bl, int tid) {
#pragma unroll
    for (int ci = 0; ci < 4; ++ci) {
        int c = tid + ci * 256;
        int s = c >> 9, g = (c >> 6) & 7, lc = c & 63;
        int row = g * 16 + (lc & 15);
        int col = kbase + s * 32 + (lc >> 4) * 8;
        uint4 v = *reinterpret_cast<const uint4*>(Bsrc + (size_t)row * ld + col);
        *reinterpret_cast<uint4*>(&Bl[c * 8]) = v;
    }
}

// ---------------------------------------------------------------------------
// Kernel 3: hop1 split-K GEMM.  P1[s][e][d] = sum_{n in chunk s} H[n][e]*x1b[n][d]
// A = H^T tile, frags loaded directly from global (coalesced along e), cast bf16.
// Grid (128 e-tiles of 64, 4 k-chunks of 8192). Block 256 = 4 waves x 16 rows.
// ---------------------------------------------------------------------------
__global__ __launch_bounds__(256) void hop1_kernel(const float* __restrict__ H,
                                                   const unsigned short* __restrict__ x1bT,
                                                   float* __restrict__ P1) {
    __shared__ unsigned short Bl[8192];   // 16 KiB
    const int tid  = threadIdx.x;
    const int lane = tid & 63;
    const int wave = tid >> 6;
    const int q    = lane >> 4;
    const int mi   = lane & 15;
    const int e0   = blockIdx.x * 64;
    const int k0   = blockIdx.y * 8192;
    const int eA   = e0 + wave * 16 + mi;

    v4f acc[8];
#pragma unroll
    for (int g = 0; g < 8; ++g) acc[g] = (v4f){0.f, 0.f, 0.f, 0.f};

    for (int kb = 0; kb < 128; ++kb) {
        const int kbase = k0 + kb * 64;
        stage_B(x1bT, (size_t)NN, kbase, Bl, tid);
        __syncthreads();
#pragma unroll
        for (int s = 0; s < 2; ++s) {
            const float* hp = H + (size_t)(kbase + s * 32 + q * 8) * EE + eA;
            v8s a;
#pragma unroll
            for (int j = 0; j < 8; ++j) a[j] = (short)f2bf(hp[(size_t)j * EE]);
#pragma unroll
            for (int g = 0; g < 8; ++g) {
                v8s b = *reinterpret_cast<const v8s*>(&Bl[((s * 8 + g) * 64 + lane) * 8]);
                acc[g] = __builtin_amdgcn_mfma_f32_16x16x32_bf16(a, b, acc[g], 0, 0, 0);
            }
        }
        __syncthreads();
    }
    float* out = P1 + (size_t)blockIdx.y * (EE * DD);
#pragma unroll
    for (int g = 0; g < 8; ++g)
#pragma unroll
        for (int r = 0; r < 4; ++r) {
            int er = e0 + wave * 16 + q * 4 + r;          // C/D: row=(lane>>4)*4+reg
            out[(size_t)er * DD + g * 16 + mi] = acc[g][r]; // col=lane&15
        }
}

// ---------------------------------------------------------------------------
// Kernel 4: reduce split-K partials, scale by de_inv, write transposed bf16:
// MebT[d][e] = bf16( (sum_s P1[s][e][d]) / (d_e[e] + 1e-8) )
// ---------------------------------------------------------------------------
__global__ __launch_bounds__(256) void reduce1_kernel(const float* __restrict__ P1,
                                                      const float* __restrict__ d_e,
                                                      unsigned short* __restrict__ MebT) {
    __shared__ float t[128 * 65];
    const int eb = blockIdx.x * 64;
    for (int i = 0; i < 32; ++i) {
        int idx = i * 256 + threadIdx.x;
        int el = idx >> 7, d = idx & 127;
        size_t o = (size_t)(eb + el) * DD + d;
        float s = P1[o] + P1[o + (size_t)EE * DD] + P1[o + 2 * (size_t)EE * DD] +
                  P1[o + 3 * (size_t)EE * DD];
        s *= 1.f / (d_e[eb + el] + 1e-8f);
        t[d * 65 + el] = s;
    }
    __syncthreads();
    for (int i = 0; i < 32; ++i) {
        int idx = i * 256 + threadIdx.x;
        int el = idx & 63, d = idx >> 6;
        MebT[(size_t)d * EE + eb + el] = f2bf(t[d * 65 + el]);
    }
}

// ---------------------------------------------------------------------------
// Kernel 5: hop2 GEMM + fused epilogue.
// Mv[n][d] = dvinv[n] * sum_e H[n][e] * Me[e][d]; h = relu(Mv@W^T + b); LayerNorm.
// Grid 512 n-tiles of 64. A (=H) is k-contiguous, direct global frag loads.
// ---------------------------------------------------------------------------
__global__ __launch_bounds__(256) void hop2_kernel(const float* __restrict__ H,
                                                   const unsigned short* __restrict__ MebT,
                                                   const unsigned short* __restrict__ Wb,
                                                   const float* __restrict__ d_v,
                                                   const float* __restrict__ bias,
                                                   const float* __restrict__ gamma,
                                                   const float* __restrict__ beta,
                                                   float* __restrict__ out) {
    __shared__ unsigned short Bl[8192];   // 16 KiB
    __shared__ float Mv[64 * 129];        // 33 KiB
    const int tid  = threadIdx.x;
    const int lane = tid & 63;
    const int wave = tid >> 6;
    const int q    = lane >> 4;
    const int mi   = lane & 15;
    const int n0   = blockIdx.x * 64;
    const int nA   = n0 + wave * 16 + mi;

    v4f acc[8];
#pragma unroll
    for (int g = 0; g < 8; ++g) acc[g] = (v4f){0.f, 0.f, 0.f, 0.f};

    for (int kb = 0; kb < 128; ++kb) {
        const int kbase = kb * 64;
        stage_B(MebT, (size_t)EE, kbase, Bl, tid);
        __syncthreads();
#pragma unroll
        for (int s = 0; s < 2; ++s) {
            const float* hp = H + (size_t)nA * EE + kbase + s * 32 + q * 8;
            const float4 f0 = *reinterpret_cast<const float4*>(hp);
            const float4 f1 = *reinterpret_cast<const float4*>(hp + 4);
            v8s a;
            a[0] = (short)f2bf(f0.x); a[1] = (short)f2bf(f0.y);
            a[2] = (short)f2bf(f0.z); a[3] = (short)f2bf(f0.w);
            a[4] = (short)f2bf(f1.x); a[5] = (short)f2bf(f1.y);
            a[6] = (short)f2bf(f1.z); a[7] = (short)f2bf(f1.w);
#pragma unroll
            for (int g = 0; g < 8; ++g) {
                v8s b = *reinterpret_cast<const v8s*>(&Bl[((s * 8 + g) * 64 + lane) * 8]);
                acc[g] = __builtin_amdgcn_mfma_f32_16x16x32_bf16(a, b, acc[g], 0, 0, 0);
            }
        }
        __syncthreads();
    }

    // dvinv scale -> LDS (fp32)
#pragma unroll
    for (int r = 0; r < 4; ++r) {
        int row = wave * 16 + q * 4 + r;
        float dvi = 1.f / (sqrtf(d_v[n0 + row]) + 1e-8f);
#pragma unroll
        for (int g = 0; g < 8; ++g) Mv[row * 129 + g * 16 + mi] = acc[g][r] * dvi;
    }
    __syncthreads();

    // linear: h = Mv @ W^T via MFMA (A from LDS, B = Wb[do][di] direct)
    v4f h[8];
#pragma unroll
    for (int g = 0; g < 8; ++g) h[g] = (v4f){0.f, 0.f, 0.f, 0.f};
#pragma unroll
    for (int ks = 0; ks < 4; ++ks) {
        const int rowA = wave * 16 + mi;
        v8s a;
#pragma unroll
        for (int j = 0; j < 8; ++j)
            a[j] = (short)f2bf(Mv[rowA * 129 + ks * 32 + q * 8 + j]);
#pragma unroll
        for (int g = 0; g < 8; ++g) {
            v8s bw = *reinterpret_cast<const v8s*>(
                Wb + (size_t)(g * 16 + mi) * DD + ks * 32 + q * 8);
            h[g] = __builtin_amdgcn_mfma_f32_16x16x32_bf16(a, bw, h[g], 0, 0, 0);
        }
    }

    // bias + relu + LayerNorm (rows live in 16-lane groups; reduce over mi & g)
    float sum[4] = {0.f, 0.f, 0.f, 0.f}, sq[4] = {0.f, 0.f, 0.f, 0.f};
#pragma unroll
    for (int g = 0; g < 8; ++g)
#pragma unroll
        for (int r = 0; r < 4; ++r) {
            float v = h[g][r] + bias[g * 16 + mi];
            v = fmaxf(v, 0.f);
            h[g][r] = v;
            sum[r] += v; sq[r] += v * v;
        }
#pragma unroll
    for (int m = 1; m <= 8; m <<= 1)
#pragma unroll
        for (int r = 0; r < 4; ++r) {
            sum[r] += __shfl_xor(sum[r], m);
            sq[r]  += __shfl_xor(sq[r], m);
        }
    float mu[4], rstd[4];
#pragma unroll
    for (int r = 0; r < 4; ++r) {
        mu[r] = sum[r] * (1.f / 128.f);
        float var = sq[r] * (1.f / 128.f) - mu[r] * mu[r];
        rstd[r] = rsqrtf(var + 1e-5f);
    }
#pragma unroll
    for (int g = 0; g < 8; ++g)
#pragma unroll
        for (int r = 0; r < 4; ++r) {
            int row = n0 + wave * 16 + q * 4 + r;
            int col = g * 16 + mi;
            out[(size_t)row * DD + col] =
                gamma[col] * (h[g][r] - mu[r]) * rstd[r] + beta[col];
        }
}

// ---------------------------------------------------------------------------
extern "C" void kernel_launch(void* const* d_in, const int* in_sizes, int n_in,
                              void* d_out, int out_size, void* d_ws, size_t ws_size,
                              hipStream_t stream) {
    const float* x     = (const float*)d_in[0];
    const float* H     = (const float*)d_in[1];
    const float* W     = (const float*)d_in[2];
    const float* bias  = (const float*)d_in[3];
    const float* gamma = (const float*)d_in[4];
    const float* beta  = (const float*)d_in[5];
    float* out = (float*)d_out;

    char* ws = (char*)d_ws;
    float*          d_v  = (float*)ws;                       // 131072 B
    float*          d_e  = (float*)(ws + 131072);            // 32768 B
    unsigned short* x1bT = (unsigned short*)(ws + 163840);   // 8 MiB
    unsigned short* MebT = (unsigned short*)(ws + 8552448);  // 2 MiB
    unsigned short* Wb   = (unsigned short*)(ws + 10649600); // 32 KiB
    float*          P1   = (float*)(ws + 10682368);          // 16 MiB (4 x E x D)
    // total ~27.5 MiB of d_ws

    hipMemsetAsync(ws, 0, 163840, stream);  // zero d_v, d_e (atomic targets)
    deg_kernel    <<<dim3(32, 64), 256, 0, stream>>>(H, d_v, d_e);
    prep_kernel   <<<513, 256, 0, stream>>>(x, W, d_v, x1bT, Wb);
    hop1_kernel   <<<dim3(128, 4), 256, 0, stream>>>(H, x1bT, P1);
    reduce1_kernel<<<128, 256, 0, stream>>>(P1, d_e, MebT);
    hop2_kernel   <<<512, 256, 0, stream>>>(H, MebT, Wb, d_v, bias, gamma, beta, out);
}